// Round 21
// baseline (44.130 us; speedup 1.0000x reference)
//
#include <hip/hip_runtime.h>
#include <math.h>

#define HH 64
#define WW 64
#define CC 256
#define NHEAD 8
#define HD 32
#define KW 7

#define KR 40    // Ks row stride (u16)
#define VTS 232  // Vt row stride (u16)
#define QS 40    // Qs row stride (u16)

// natq LDS offsets (bytes)
#define XCO 0        // x-halo chunk: 224 rows x 64 f16 (swizzled) = 28672
#define WSO 28672    // W chunk: 96 rows x 64 f16 = 12288
#define KSO 40960    // Ks: 224*40*2 = 17920
#define VTO 58880    // Vt: 32*232*2 = 14848
#define QSO 73728    // Qs: 64*40*2 = 5120
#define RSO 78848    // Rs: 169*4 = 676
#define SMB 79536

typedef _Float16 half8v __attribute__((ext_vector_type(8)));
typedef __fp16 fp16x2 __attribute__((ext_vector_type(2)));
typedef float float4v __attribute__((ext_vector_type(4)));

__device__ __forceinline__ unsigned pkrtz(float lo, float hi) {
  union { fp16x2 h; unsigned u; } c;
  c.h = __builtin_amdgcn_cvt_pkrtz(lo, hi);
  return c.u;
}
__device__ __forceinline__ ushort f2h(float f) {
  union { _Float16 h; ushort u; } c;
  c.h = (_Float16)f;
  return c.u;
}

// ---- f16 MFMA GEMM (R12's gemm5h, proven) — used for output projection -----
template <int N, int BM, int BN, bool ABF, bool OB>
__global__ __launch_bounds__(256) void gemm5h(
    const void* __restrict__ Ap, const float* __restrict__ Bw,
    const float* __restrict__ bias, void* __restrict__ Cd) {
  constexpr int SEGA = BM / 32;
  constexpr int SEGB = BN / 32;
  constexpr int MF = BM / 32;
  constexpr int NF = BN / 32;

  __shared__ ushort As[2][BM * 64];
  __shared__ ushort Bs[2][BN * 64];

  const int t = threadIdx.x;
  const int lane = t & 63;
  const int wave = t >> 6;
  const int bm = blockIdx.x * BM;
  const int bn = blockIdx.y * BN;

  const float*  Aw = (const float*)Ap;
  const ushort* Ab = (const ushort*)Ap;

  float fA[2][SEGA][8];
  float fB[2][SEGB][8];
  uint4 wA[2][SEGA];

#define LOADA(c, s)                                                            \
  {                                                                            \
    _Pragma("unroll") for (int sa = 0; sa < SEGA; ++sa) {                      \
      const int seg = sa * 256 + t;                                            \
      const int row = seg >> 3;                                                \
      const int q8 = seg & 7;                                                  \
      if (ABF) {                                                               \
        wA[s][sa] =                                                            \
            *(const uint4*)(Ab + (size_t)(bm + row) * 256 + (c) * 64 + q8 * 8);\
      } else {                                                                 \
        const float* p_ = Aw + (size_t)(bm + row) * 256 + (c) * 64 + q8 * 8;   \
        *(float4*)&fA[s][sa][0] = *(const float4*)(p_);                        \
        *(float4*)&fA[s][sa][4] = *(const float4*)(p_ + 4);                    \
      }                                                                        \
    }                                                                          \
  }

#define LOADB(c, s)                                                            \
  {                                                                            \
    _Pragma("unroll") for (int sb = 0; sb < SEGB; ++sb) {                      \
      const int seg = sb * 256 + t;                                            \
      const int row = seg >> 3;                                                \
      const int q8 = seg & 7;                                                  \
      const float* p_ = Bw + (size_t)(bn + row) * 256 + (c) * 64 + q8 * 8;     \
      *(float4*)&fB[s][sb][0] = *(const float4*)(p_);                          \
      *(float4*)&fB[s][sb][4] = *(const float4*)(p_ + 4);                      \
    }                                                                          \
  }

#define WRITEC(b, s)                                                           \
  {                                                                            \
    _Pragma("unroll") for (int sa = 0; sa < SEGA; ++sa) {                      \
      const int seg = sa * 256 + t;                                            \
      const int row = seg >> 3;                                                \
      const int q8 = seg & 7;                                                  \
      const int lin = row * 128 + q8 * 16;                                     \
      const int sw = (row & 7) << 4;                                           \
      uint4 w_;                                                                \
      if (ABF) {                                                               \
        w_ = wA[s][sa];                                                        \
      } else {                                                                 \
        w_.x = pkrtz(fA[s][sa][0], fA[s][sa][1]);                              \
        w_.y = pkrtz(fA[s][sa][2], fA[s][sa][3]);                              \
        w_.z = pkrtz(fA[s][sa][4], fA[s][sa][5]);                              \
        w_.w = pkrtz(fA[s][sa][6], fA[s][sa][7]);                              \
      }                                                                        \
      *(uint4*)((char*)As[b] + (lin ^ sw)) = w_;                               \
    }                                                                          \
    _Pragma("unroll") for (int sb = 0; sb < SEGB; ++sb) {                      \
      const int seg = sb * 256 + t;                                            \
      const int row = seg >> 3;                                                \
      const int q8 = seg & 7;                                                  \
      const int lin = row * 128 + q8 * 16;                                     \
      const int sw = (row & 7) << 4;                                           \
      uint4 w_;                                                                \
      w_.x = pkrtz(fB[s][sb][0], fB[s][sb][1]);                                \
      w_.y = pkrtz(fB[s][sb][2], fB[s][sb][3]);                                \
      w_.z = pkrtz(fB[s][sb][4], fB[s][sb][5]);                                \
      w_.w = pkrtz(fB[s][sb][6], fB[s][sb][7]);                                \
      *(uint4*)((char*)Bs[b] + (lin ^ sw)) = w_;                               \
    }                                                                          \
  }

  const int wr = (wave >> 1) * (BM / 2);
  const int wc = (wave & 1) * (BN / 2);
  const int lrow = lane & 15;
  const int lkb = (lane >> 4) * 16;

  float4v acc[MF][NF];
#pragma unroll
  for (int mf = 0; mf < MF; ++mf)
#pragma unroll
    for (int nf = 0; nf < NF; ++nf) acc[mf][nf] = (float4v){0.f, 0.f, 0.f, 0.f};

  LOADA(0, 0); LOADB(0, 0);
  WRITEC(0, 0);
  LOADA(1, 1); LOADB(1, 1);
  __syncthreads();

#pragma unroll
  for (int c = 0; c < 4; ++c) {
    if (c < 3) WRITEC((c + 1) & 1, (c + 1) & 1);
    if (c < 2) { LOADA(c + 2, c & 1); LOADB(c + 2, c & 1); }
    const char* Al = (const char*)As[c & 1];
    const char* Bl = (const char*)Bs[c & 1];
#pragma unroll
    for (int ks = 0; ks < 2; ++ks) {
      half8v af[MF], bfr[NF];
#pragma unroll
      for (int mf = 0; mf < MF; ++mf) {
        const int row = wr + mf * 16 + lrow;
        const int ad = row * 128 + ks * 64 + lkb;
        af[mf] = *(const half8v*)(Al + (ad ^ ((row & 7) << 4)));
      }
#pragma unroll
      for (int nf = 0; nf < NF; ++nf) {
        const int row = wc + nf * 16 + lrow;
        const int bd = row * 128 + ks * 64 + lkb;
        bfr[nf] = *(const half8v*)(Bl + (bd ^ ((row & 7) << 4)));
      }
#pragma unroll
      for (int mf = 0; mf < MF; ++mf)
#pragma unroll
        for (int nf = 0; nf < NF; ++nf)
          acc[mf][nf] = __builtin_amdgcn_mfma_f32_16x16x32_f16(
              af[mf], bfr[nf], acc[mf][nf], 0, 0, 0);
    }
    if (c < 3) __syncthreads();
  }
#undef LOADA
#undef LOADB
#undef WRITEC

#pragma unroll
  for (int mf = 0; mf < MF; ++mf) {
#pragma unroll
    for (int nf = 0; nf < NF; ++nf) {
      const int n = bn + wc + nf * 16 + lrow;
      const float bv = bias[n];
      const int m0 = bm + wr + mf * 16 + (lane >> 4) * 4;
      if (OB) {
        ushort* C = (ushort*)Cd;
#pragma unroll
        for (int rr = 0; rr < 4; ++rr)
          C[(size_t)(m0 + rr) * N + n] = f2h(acc[mf][nf][rr] + bv);
      } else {
        float* C = (float*)Cd;
#pragma unroll
        for (int rr = 0; rr < 4; ++rr)
          C[(size_t)(m0 + rr) * N + n] = acc[mf][nf][rr] + bv;
      }
    }
  }
}

// ---- natq: fused block-local QKV mini-GEMM + R13 natten ---------------------
// grid (64 tiles, 8 heads), 256 thr. Phase A: compute K[224][32], Vt[32][224],
// Q[64][32] for this (tile,head) from x + qkv_w slices via MFMA, with output
// layouts landing directly in natten's LDS layouts (V via swapped operands).
// Phase B: R13's natten7 body verbatim. No qkvh intermediate, no extra dispatch.
__global__ __launch_bounds__(256) void natq(
    const float* __restrict__ x, const float* __restrict__ qkv_w,
    const float* __restrict__ qkv_b, const float* __restrict__ rpb,
    ushort* __restrict__ aout) {
  __shared__ __align__(16) char smem[SMB];
  char* Xc = smem + XCO;
  char* Wsb = smem + WSO;
  ushort* Ks = (ushort*)(smem + KSO);
  ushort* Vt = (ushort*)(smem + VTO);
  ushort* Qs = (ushort*)(smem + QSO);
  float* Rs = (float*)(smem + RSO);

  const int tile = blockIdx.x;
  const int h = blockIdx.y;
  const int t = threadIdx.x;
  const int l = t & 63;
  const int wv = t >> 6;
  const int lg = l >> 4;   // 0..3
  const int l15 = l & 15;
  const int lkb = lg * 16; // lane's k-slice byte offset (8 f16)

  const int i0 = (tile >> 3) * 8, j0 = (tile & 7) * 8;
  const int hs = min(max(i0 - 3, 0), HH - 14);
  const int ws = min(max(j0 - 3, 0), WW - 14);
  const int di = i0 - hs, dj = j0 - ws;  // 0..6

  if (t < 169) Rs[t] = rpb[h * 169 + t];

  const float4v zz = {0.f, 0.f, 0.f, 0.f};
  float4v acc[18];
#pragma unroll
  for (int idx = 0; idx < 18; ++idx) acc[idx] = zz;

  // frag reads from swizzled BK=64 chunk layouts (gemm5h pattern)
#define XF(row, k2)                                                            \
  (*(const half8v*)(Xc + ((((row) * 128) + (k2) * 64 + lkb) ^                  \
                          (((row) & 7) << 4))))
#define WF(row, k2)                                                            \
  (*(const half8v*)(Wsb + ((((row) * 128) + (k2) * 64 + lkb) ^                 \
                           (((row) & 7) << 4))))

  for (int c = 0; c < 4; ++c) {
    // ---- stage x-halo chunk (224 entries x 64, pad cols -> 0) ----
#pragma unroll
    for (int sa = 0; sa < 7; ++sa) {
      const int seg = sa * 256 + t;
      const int row = seg >> 3;   // entry 0..223 = hr*16+hc
      const int q8 = seg & 7;
      const int lin = row * 128 + q8 * 16;
      const int swz = (row & 7) << 4;
      const int hr = row >> 4, hc = row & 15;
      uint4 w_;
      if (hc < 14) {
        const float* p_ =
            x + (size_t)((hs + hr) * WW + ws + hc) * 256 + c * 64 + q8 * 8;
        const float4 f0 = *(const float4*)(p_);
        const float4 f1 = *(const float4*)(p_ + 4);
        w_.x = pkrtz(f0.x, f0.y);
        w_.y = pkrtz(f0.z, f0.w);
        w_.z = pkrtz(f1.x, f1.y);
        w_.w = pkrtz(f1.z, f1.w);
      } else {
        w_.x = 0u; w_.y = 0u; w_.z = 0u; w_.w = 0u;
      }
      *(uint4*)(Xc + (lin ^ swz)) = w_;
    }
    // ---- stage W chunk: rows 0-31 Wk, 32-63 Wv, 64-95 Wq (this head) ----
#pragma unroll
    for (int sb = 0; sb < 3; ++sb) {
      const int seg = sb * 256 + t;
      const int row = seg >> 3;   // 0..95
      const int q8 = seg & 7;
      const int lin = row * 128 + q8 * 16;
      const int swz = (row & 7) << 4;
      const int wrow = (row < 32) ? (256 + h * HD + row)
                     : (row < 64) ? (512 + h * HD + (row - 32))
                                  : (h * HD + (row - 64));
      const float* p_ = qkv_w + (size_t)wrow * 256 + c * 64 + q8 * 8;
      const float4 f0 = *(const float4*)(p_);
      const float4 f1 = *(const float4*)(p_ + 4);
      uint4 w_;
      w_.x = pkrtz(f0.x, f0.y);
      w_.y = pkrtz(f0.z, f0.w);
      w_.z = pkrtz(f1.x, f1.y);
      w_.w = pkrtz(f1.z, f1.w);
      *(uint4*)(Wsb + (lin ^ swz)) = w_;
    }
    __syncthreads();

    // ---- 18 frags/wave: gf 0-27 K, 28-55 V(swapped), 56-71 Q ----
#pragma unroll
    for (int k2 = 0; k2 < 2; ++k2) {
#pragma unroll
      for (int idx = 0; idx < 18; ++idx) {
        const int gf = wv * 18 + idx;
        half8v af, bf;
        if (gf < 28) {          // K: D[entry][dim]
          const int mf = gf >> 1, dh = gf & 1;
          af = XF(mf * 16 + l15, k2);
          bf = WF(dh * 16 + l15, k2);
        } else if (gf < 56) {   // V: D[dim][entry] (swapped -> free transpose)
          const int v = gf - 28;
          const int mf = v >> 1, dh = v & 1;
          af = WF(32 + dh * 16 + l15, k2);
          bf = XF(mf * 16 + l15, k2);
        } else {                // Q: D[entry][dim], pixel-row frags only
          const int q = gf - 56;
          const int mfq = q >> 1, dh = q & 1;
          af = XF((di + mfq) * 16 + l15, k2);
          bf = WF(64 + dh * 16 + l15, k2);
        }
        acc[idx] =
            __builtin_amdgcn_mfma_f32_16x16x32_f16(af, bf, acc[idx], 0, 0, 0);
      }
    }
    __syncthreads();
  }
#undef XF
#undef WF

  // ---- write K/Vt/Qs to natten LDS layouts (+ bias) ----
#pragma unroll
  for (int idx = 0; idx < 18; ++idx) {
    const int gf = wv * 18 + idx;
    if (gf < 28) {
      const int mf = gf >> 1, dh = gf & 1;
      const int dim = dh * 16 + l15;
      const float bv = qkv_b[256 + h * HD + dim];
#pragma unroll
      for (int r = 0; r < 4; ++r) {
        const int ent = mf * 16 + lg * 4 + r;
        Ks[ent * KR + dim] = f2h(acc[idx][r] + bv);
      }
    } else if (gf < 56) {
      const int v = gf - 28;
      const int mf = v >> 1, dh = v & 1;
      const int ent = mf * 16 + l15;
#pragma unroll
      for (int r = 0; r < 4; ++r) {
        const int dim = dh * 16 + lg * 4 + r;
        Vt[dim * VTS + ent] = f2h(acc[idx][r] + qkv_b[512 + h * HD + dim]);
      }
    } else {
      const int q = gf - 56;
      const int mfq = q >> 1, dh = q & 1;
      const int dim = dh * 16 + l15;
      const float bv = qkv_b[h * HD + dim];
#pragma unroll
      for (int r = 0; r < 4; ++r) {
        const int pos = lg * 4 + r;      // hc within halo row
        const int pc = pos - dj;
        if ((unsigned)pc < 8u)
          Qs[(mfq * 8 + pc) * QS + dim] = f2h(acc[idx][r] + bv);
      }
    }
  }
  __syncthreads();

  // ---- Phase B: R13's natten7 body (verbatim; qf from Qs) ----
  const int strip_i0 = i0 + wv * 2;
  const int pi = strip_i0 + (l15 >> 3);
  const int pj = j0 + (l15 & 7);
  const int si = min(max(pi - 3, 0), HH - KW);
  const int sj = min(max(pj - 3, 0), WW - KW);
  const int si_min = min(max(strip_i0 - 3, 0), HH - KW);
  const int slab0 = min(si_min - hs, 6);

  const int px = (wv * 2 + (l15 >> 3)) * 8 + (l15 & 7);
  const half8v qf = *(const half8v*)(Qs + px * QS + lg * 8);

  float4v s8[8];
#pragma unroll
  for (int g = 0; g < 8; ++g) {
    const int ent = (slab0 + g) * 16 + l15;
    const half8v kf = *(const half8v*)(Ks + ent * KR + lg * 8);
    s8[g] = __builtin_amdgcn_mfma_f32_16x16x32_f16(kf, qf, zz, 0, 0, 0);
  }

  const int lr0 = si - hs;
  const int lc0 = sj - ws;
  const int abase = slab0 - lr0;
  const int rowb = ((si - pi + 6) + abase) * 13 + (sj - pj + 6) - lc0;
  const float scale = 0.17677669529663687f;

  float e8[8][4];
  float ssum = 0.f;
#pragma unroll
  for (int g = 0; g < 8; ++g) {
    const int a = abase + g;
    const bool va = (unsigned)a < 7u;
    const int idxg = min(max(rowb + g * 13, 0), 153);
#pragma unroll
    for (int r = 0; r < 4; ++r) {
      const int hc = lg * 4 + r;
      const bool vc = (unsigned)(hc - lc0) < 7u;
      const float ev = __expf(fmaf(s8[g][r], scale, Rs[idxg + hc]));
      const float em = (va && vc) ? ev : 0.f;
      e8[g][r] = em;
      ssum += em;
    }
  }
  ssum += __shfl_xor(ssum, 16);
  ssum += __shfl_xor(ssum, 32);
  const float inv = 1.f / ssum;

  unsigned Wp[8][2];
#pragma unroll
  for (int g = 0; g < 8; ++g) {
    Wp[g][0] = pkrtz(e8[g][0] * inv, e8[g][1] * inv);
    Wp[g][1] = pkrtz(e8[g][2] * inv, e8[g][3] * inv);
  }

  float4v o[2] = {zz, zz};
#pragma unroll
  for (int ks = 0; ks < 4; ++ks) {
    unsigned F[4];
#pragma unroll
    for (int f = 0; f < 4; ++f) {
      const int src = l15 + (((lg & 1) * 2 + (f >> 1)) << 4);
      const unsigned va = __shfl(Wp[2 * ks][f & 1], src);
      const unsigned vb = __shfl(Wp[2 * ks + 1][f & 1], src);
      F[f] = (lg >> 1) ? vb : va;
    }
    union { unsigned u[4]; half8v hh; } pf;
    pf.u[0] = F[0]; pf.u[1] = F[1]; pf.u[2] = F[2]; pf.u[3] = F[3];
#pragma unroll
    for (int nf = 0; nf < 2; ++nf) {
      const int dim = l15 + nf * 16;
      const half8v vf = *(const half8v*)(Vt + dim * VTS + slab0 * 16 +
                                         ks * 32 + lg * 8);
      o[nf] = __builtin_amdgcn_mfma_f32_16x16x32_f16(pf.hh, vf, o[nf], 0, 0, 0);
    }
  }

#pragma unroll
  for (int r = 0; r < 4; ++r) {
    const int pxo = lg * 4 + r;
    const int oi = strip_i0 + (pxo >> 3);
    const int oj = j0 + (pxo & 7);
    ushort* op = aout + (size_t)(oi * WW + oj) * CC + h * HD + l15;
    op[0]  = f2h(o[0][r]);
    op[16] = f2h(o[1][r]);
  }
}

extern "C" void kernel_launch(void* const* d_in, const int* in_sizes, int n_in,
                              void* d_out, int out_size, void* d_ws, size_t ws_size,
                              hipStream_t stream) {
  const float* x      = (const float*)d_in[0];
  const float* qkv_w  = (const float*)d_in[1];
  const float* qkv_b  = (const float*)d_in[2];
  const float* proj_w = (const float*)d_in[3];
  const float* proj_b = (const float*)d_in[4];
  const float* rpb    = (const float*)d_in[5];
  float* out = (float*)d_out;

  ushort* aouth = (ushort*)d_ws;  // [4096,256] f16

  // 1) fused QKV-mini-gemm + neighborhood attention (no qkvh intermediate)
  natq<<<dim3(64, NHEAD), 256, 0, stream>>>(x, qkv_w, qkv_b, rpb, aouth);

  // 2) output projection: 32x32 tiles, 1024 blocks (4/CU)
  gemm5h<256, 32, 32, true, false><<<dim3(128, 8), 256, 0, stream>>>(
      aouth, proj_w, proj_b, out);
}